// Round 6
// baseline (164.197 us; speedup 1.0000x reference)
//
#include <hip/hip_runtime.h>

// Quanvolution: 8x1x128x128 input, K=3, STRIDE=2 -> 63x63 patches per image,
// 9-qubit statevector sim per patch, output (8, 9, 63, 63) PauliZ expvals.
//
// Layout: one wave (64 lanes) per patch. 512 amplitudes -> 8 complex per lane.
// Amplitude index bits: [2:0] = register slot r, [8:3] = lane id.
//
// R6 changes vs R5 (passed, 152 us bench / 110 us steady):
//  - State and all gate arithmetic in packed float2 (re,im). CDNA4 has
//    v_pk_fma_f32/v_pk_mul_f32 (2 FP32/issue); complex MACs map onto packed
//    pairs with op_sel/neg modifiers (broadcast/swap/neg free). Target: halve
//    the ~2240 VALU/wave to ~1250. DS (b32 swizzles, 2 per complex) unchanged.
//  - Everything else (product state, partial rings, absorbed final ring,
//    deferred-CNOT column swaps, measurement masks) identical to R5.

namespace {

constexpr int OUT_HW = 63;
constexpr int PPB = 4;                                  // waves (patches) per block
constexpr int N_PATCH_TOTAL = 8 * OUT_HW * OUT_HW;      // 31752 == 7938 * 4

typedef float v2f __attribute__((ext_vector_type(2)));

__device__ __forceinline__ v2f swap2(v2f x) { return (v2f){x.y, x.x}; }

// complex multiply c*x as packed ops: {c.r,c.r}*x + {-c.i,c.i}*swap(x)
__device__ __forceinline__ v2f cmul2(v2f c, v2f x) {
    return (v2f){c.x, c.x} * x + (v2f){-c.y, c.y} * swap2(x);
}
// acc += c*x
__device__ __forceinline__ v2f cmac(v2f acc, v2f c, v2f x) {
    acc += (v2f){c.x, c.x} * x;
    acc += (v2f){-c.y, c.y} * swap2(x);
    return acc;
}

__device__ __forceinline__ float bperm1(int addr_bytes, float v) {
    return __int_as_float(__builtin_amdgcn_ds_bpermute(addr_bytes, __float_as_int(v)));
}
__device__ __forceinline__ v2f bperm2(int addr_bytes, v2f v) {
    v2f r;
    r.x = bperm1(addr_bytes, v.x);
    r.y = bperm1(addr_bytes, v.y);
    return r;
}

template<int M>
__device__ __forceinline__ float shflx1(float v, int lane) {
    if constexpr (M < 32)
        return __int_as_float(__builtin_amdgcn_ds_swizzle(__float_as_int(v),
                                                          0x1F | (M << 10)));
    else
        return bperm1((lane << 2) ^ 128, v);
}
template<int M>
__device__ __forceinline__ v2f shflx2(v2f v, int lane) {
    v2f r;
    r.x = shflx1<M>(v.x, lane);
    r.y = shflx1<M>(v.y, lane);
    return r;
}

// General 2x2 unitary on qubit Q; u** are complex pairs (may be per-lane).
template<int Q>
__device__ __forceinline__ void gate1q(v2f (&a)[8], int lane,
                                       v2f u00, v2f u01, v2f u10, v2f u11)
{
    if constexpr (Q < 3) {
        constexpr int qm = 1 << Q;
        #pragma unroll
        for (int r = 0; r < 8; ++r) {
            if (!(r & qm)) {
                const int r1 = r | qm;
                const v2f x = a[r], y = a[r1];
                a[r]  = cmac(cmul2(u00, x), u01, y);
                a[r1] = cmac(cmul2(u10, x), u11, y);
            }
        }
    } else {
        constexpr int lm = 1 << (Q - 3);
        const bool bit = ((lane >> (Q - 3)) & 1) != 0;
        const v2f cs = bit ? u11 : u00;   // self coefficient
        const v2f cp = bit ? u10 : u01;   // partner coefficient
        #pragma unroll
        for (int r = 0; r < 8; ++r) {
            const v2f b = shflx2<lm>(a[r], lane);
            a[r] = cmac(cmul2(cs, a[r]), cp, b);
        }
    }
}

// Reg-reg CNOT (pure rename).
template<int C, int T>
__device__ __forceinline__ void cnot(v2f (&a)[8])
{
    static_assert(C < 3 && T < 3, "only reg-reg CNOTs instantiated");
    constexpr int cm = 1 << C, tm = 1 << T;
    #pragma unroll
    for (int r = 0; r < 8; ++r) {
        if ((r & cm) && !(r & tm)) {
            const int r1 = r | tm;
            const v2f t = a[r];
            a[r] = a[r1];
            a[r1] = t;
        }
    }
}

// Ring r=1 minus trailing cnot(8,0) (deferred as column swap):
// (0,1)(1,2) renames; (2,3)..(7,8) -> src_lane = lane ^ ((lane&31)<<1) ^ bit2(reg)
__device__ __forceinline__ void ring1_partial(v2f (&a)[8], int lane)
{
    cnot<0,1>(a);
    cnot<1,2>(a);
    const int sA = (lane ^ ((lane & 31) << 1)) << 2;
    const int sB = sA ^ 4;
    #pragma unroll
    for (int r = 0; r < 8; ++r)
        a[r] = bperm2((r & 4) ? sB : sA, a[r]);
}

// Ring r=2 minus trailing cnot(7,0),cnot(8,1) (deferred):
// (0,2) rename; (1,3)..(6,8) -> src_lane = lane ^ ((lane&15)<<2) ^ bit1 ^ bit2<<1
__device__ __forceinline__ void ring2_partial(v2f (&a)[8], int lane)
{
    cnot<0,2>(a);
    const int s0 = (lane ^ ((lane & 15) << 2)) << 2;
    #pragma unroll
    for (int r = 0; r < 8; ++r) {
        const int ad = s0 ^ (((r >> 1) & 1) << 2) ^ (((r >> 2) & 1) << 3);
        a[r] = bperm2(ad, a[r]);
    }
}

// Precompute the 18 Rot matrices (weights shared across all patches).
// rot[(l*9+q)*8 + {0..7}] = u00.re,u00.im,u01.re,u01.im,u10.re,u10.im,u11.re,u11.im
__global__ void rot_precomp_kernel(const float* __restrict__ w, float* __restrict__ rot)
{
    const int i = threadIdx.x;
    if (i >= 18) return;
    const float phi = w[i*3 + 0], theta = w[i*3 + 1], omega = w[i*3 + 2];
    const float ct = cosf(0.5f * theta), st = sinf(0.5f * theta);
    const float apo = 0.5f * (phi + omega), amo = 0.5f * (phi - omega);
    const float ca = cosf(apo), sa = sinf(apo);
    const float cm = cosf(amo), sm = sinf(amo);
    float* m = rot + i * 8;
    m[0] =  ca * ct; m[1] = -sa * ct;   // u00
    m[2] = -cm * st; m[3] = -sm * st;   // u01
    m[4] =  cm * st; m[5] = -sm * st;   // u10
    m[6] =  ca * ct; m[7] =  sa * ct;   // u11
}

#define APPLY_ROT(q) { const v2f* M = (const v2f*)(m + 8*(q)); \
    gate1q<q>(a, lane, M[0], M[1], M[2], M[3]); }

// Rot with a deferred CNOT absorbed: columns swapped on lanes where sw is set.
#define APPLY_ROT_SW(q, sw) { const v2f* M = (const v2f*)(m + 8*(q)); \
    const v2f w00 = (sw) ? M[1] : M[0]; \
    const v2f w01 = (sw) ? M[0] : M[1]; \
    const v2f w10 = (sw) ? M[3] : M[2]; \
    const v2f w11 = (sw) ? M[2] : M[3]; \
    gate1q<q>(a, lane, w00, w01, w10, w11); }

// sign-apply: v * (-1)^par  (par in {0,1})
__device__ __forceinline__ float sgn_apply(float v, int par) {
    return __int_as_float(__float_as_int(v) ^ (par << 31));
}

__global__ __launch_bounds__(PPB * 64, 6) void qconv_kernel(
    const float* __restrict__ x,      // (8, 1, 128, 128)
    const float* __restrict__ rot,    // (2, 9, 8) precomputed Rot matrices
    float* __restrict__ out)          // (8, 9, 63, 63)
{
    const int lane  = threadIdx.x & 63;
    const int wv    = threadIdx.x >> 6;
    const int patch = blockIdx.x * PPB + wv;
    if (patch >= N_PATCH_TOTAL) return;          // wave-uniform (never taken)

    const int b   = patch / (OUT_HW * OUT_HW);
    const int rem = patch - b * (OUT_HW * OUT_HW);
    const int oy  = rem / OUT_HW;
    const int ox  = rem - oy * OUT_HW;

    const float* xp = x + b * 16384 + (oy * 2) * 128 + (ox * 2);

    // ---- Product state after RX encode + Rot(l=0):
    // (alpha,beta) = first column of Rot(l0,q)*RX(a_q):
    //   alpha = {c,c}*u00 + {s,-s}*swap(u01)
    //   beta  = {c,c}*u10 + {s,-s}*swap(u11)
    v2f a[8];
    {
        v2f L = (v2f){1.0f, 0.0f};               // lane factor (qubits 3..8)
        #pragma unroll
        for (int q = 3; q < 9; ++q) {
            const float ang = xp[(q / 3) * 128 + (q % 3)];
            float s, c;
            __sincosf(0.5f * ang, &s, &c);
            const v2f* M = (const v2f*)(rot + 8 * q);
            const v2f alpha = (v2f){c, c} * M[0] + (v2f){s, -s} * swap2(M[1]);
            const v2f beta  = (v2f){c, c} * M[2] + (v2f){s, -s} * swap2(M[3]);
            const bool bit = ((lane >> (q - 3)) & 1) != 0;
            const v2f f = bit ? beta : alpha;
            L = cmul2(L, f);
        }
        v2f al[3], be[3];
        #pragma unroll
        for (int q = 0; q < 3; ++q) {
            const float ang = xp[(q / 3) * 128 + (q % 3)];
            float s, c;
            __sincosf(0.5f * ang, &s, &c);
            const v2f* M = (const v2f*)(rot + 8 * q);
            al[q] = (v2f){c, c} * M[0] + (v2f){s, -s} * swap2(M[1]);
            be[q] = (v2f){c, c} * M[2] + (v2f){s, -s} * swap2(M[3]);
        }
        v2f c01[4];
        #pragma unroll
        for (int j = 0; j < 4; ++j) {
            const v2f f0 = (j & 1) ? be[0] : al[0];
            const v2f f1 = (j & 2) ? be[1] : al[1];
            c01[j] = cmul2(f0, f1);
        }
        #pragma unroll
        for (int r = 0; r < 8; ++r) {
            const v2f f2 = (r & 4) ? be[2] : al[2];
            const v2f g = cmul2(c01[r & 3], f2);
            a[r] = cmul2(g, L);
        }
    }

    const bool b4 = ((lane >> 4) & 1) != 0;   // amp-index bit 7
    const bool b5 = ((lane >> 5) & 1) != 0;   // amp-index bit 8

    ring1_partial(a, lane);                    // cnot(8,0) deferred into L2 q0
    {   // Layer 2: Rot(l=1); q0 absorbs CNOT(8,0) (col swap on b5)
        const float* m = rot + 72;
        APPLY_ROT_SW(0, b5)
        APPLY_ROT(1) APPLY_ROT(2) APPLY_ROT(3) APPLY_ROT(4)
        APPLY_ROT(5) APPLY_ROT(6) APPLY_ROT(7) APPLY_ROT(8)
        ring2_partial(a, lane);                // cnot(7,0),(8,1) deferred into L3
    }
    {   // Layer 3: Rot(l=0); q0 absorbs CNOT(7,0) (b4), q1 absorbs CNOT(8,1) (b5)
        const float* m = rot;
        APPLY_ROT_SW(0, b4)
        APPLY_ROT_SW(1, b5)
        APPLY_ROT(2) APPLY_ROT(3) APPLY_ROT(4)
        APPLY_ROT(5) APPLY_ROT(6) APPLY_ROT(7) APPLY_ROT(8)
        ring1_partial(a, lane);                // cnot(8,0) deferred into L4 q0
    }
    {   // Layer 4: Rot(l=1); q0 absorbs CNOT(8,0) (b5). Final ring2 absorbed
        // into measurement masks below.
        const float* m = rot + 72;
        APPLY_ROT_SW(0, b5)
        APPLY_ROT(1) APPLY_ROT(2) APPLY_ROT(3) APPLY_ROT(4)
        APPLY_ROT(5) APPLY_ROT(6) APPLY_ROT(7) APPLY_ROT(8)
    }

    // ---- Measurement with final ring2 absorbed:
    // e_q = sum_p (-1)^{parity(p & w_q)} |amp_p|^2,
    // w = {0x0AB,0x157,0x005,0x00A,0x015,0x02A,0x055,0x0AA,0x155}
    float p[8];
    #pragma unroll
    for (int r = 0; r < 8; ++r) p[r] = a[r].x * a[r].x + a[r].y * a[r].y;

    const float S3 = (p[0]+p[3]+p[4]+p[7]) - (p[1]+p[2]+p[5]+p[6]);
    const float S7 = (p[0]+p[3]+p[5]+p[6]) - (p[1]+p[2]+p[4]+p[7]);
    const float S5 = (p[0]+p[2]+p[5]+p[7]) - (p[1]+p[3]+p[4]+p[6]);
    const float S2 = (p[0]+p[1]+p[4]+p[5]) - (p[2]+p[3]+p[6]+p[7]);

    const int c0 = lane & 1, c1 = (lane >> 1) & 1, c2 = (lane >> 2) & 1;
    const int c3 = (lane >> 3) & 1, c4 = (lane >> 4) & 1, c5 = (lane >> 5) & 1;
    const int p05 = c0 ^ c2, p0A = c1 ^ c3;
    const int p15 = p05 ^ c4, p2A = p0A ^ c5;

    float e[9];
    e[0] = sgn_apply(S3, p15);   // w0 = 0x0AB: reg 3, lane 0x15
    e[1] = sgn_apply(S7, p2A);   // w1 = 0x157: reg 7, lane 0x2A
    e[2] = S5;                   // w2 = 0x005: reg 5
    e[3] = sgn_apply(S2, c0);    // w3 = 0x00A: reg 2, lane 1
    e[4] = sgn_apply(S5, c1);    // w4 = 0x015: reg 5, lane 2
    e[5] = sgn_apply(S2, p05);   // w5 = 0x02A: reg 2, lane 5
    e[6] = sgn_apply(S5, p0A);   // w6 = 0x055: reg 5, lane 0xA
    e[7] = sgn_apply(S2, p15);   // w7 = 0x0AA: reg 2, lane 0x15
    e[8] = sgn_apply(S5, p2A);   // w8 = 0x155: reg 5, lane 0x2A

    // Butterfly reduce across the 64 lanes
    #pragma unroll
    for (int q = 0; q < 9; ++q) e[q] += shflx1<1>(e[q], lane);
    #pragma unroll
    for (int q = 0; q < 9; ++q) e[q] += shflx1<2>(e[q], lane);
    #pragma unroll
    for (int q = 0; q < 9; ++q) e[q] += shflx1<4>(e[q], lane);
    #pragma unroll
    for (int q = 0; q < 9; ++q) e[q] += shflx1<8>(e[q], lane);
    #pragma unroll
    for (int q = 0; q < 9; ++q) e[q] += shflx1<16>(e[q], lane);
    #pragma unroll
    for (int q = 0; q < 9; ++q) e[q] += shflx1<32>(e[q], lane);

    // lanes 0..8 each store one channel (single predicated store)
    float v = e[0];
    v = (lane == 1) ? e[1] : v;
    v = (lane == 2) ? e[2] : v;
    v = (lane == 3) ? e[3] : v;
    v = (lane == 4) ? e[4] : v;
    v = (lane == 5) ? e[5] : v;
    v = (lane == 6) ? e[6] : v;
    v = (lane == 7) ? e[7] : v;
    v = (lane == 8) ? e[8] : v;
    if (lane < 9) {
        out[(b * 9 + lane) * (OUT_HW * OUT_HW) + oy * OUT_HW + ox] = v;
    }
}

} // anonymous namespace

extern "C" void kernel_launch(void* const* d_in, const int* in_sizes, int n_in,
                              void* d_out, int out_size, void* d_ws, size_t ws_size,
                              hipStream_t stream)
{
    const float* x = (const float*)d_in[0];   // (8,1,128,128) float32
    const float* w = (const float*)d_in[1];   // (2,9,3) float32
    float* rot = (float*)d_ws;                // 144 floats scratch
    float* out = (float*)d_out;               // (8,9,63,63) float32

    rot_precomp_kernel<<<1, 64, 0, stream>>>(w, rot);
    qconv_kernel<<<N_PATCH_TOTAL / PPB, PPB * 64, 0, stream>>>(x, rot, out);
}

// Round 7
// 159.211 us; speedup vs baseline: 1.0313x; 1.0313x over previous
//
#include <hip/hip_runtime.h>

// Quanvolution: 8x1x128x128 input, K=3, STRIDE=2 -> 63x63 patches per image,
// 9-qubit statevector sim per patch, output (8, 9, 63, 63) PauliZ expvals.
//
// Layout: one wave (64 lanes) per patch. 512 amplitudes -> 8 complex per lane.
// Amplitude index bits: [2:0] = register slot r, [8:3] = lane id.
//
// R7 change vs R6 (passed, 118 us steady but 350 MB/dispatch scratch spill):
//  - __launch_bounds__(256, 6) -> (256, 4). The v2f (packed re,im) state needs
//    even-aligned VGPR pairs; under the 6-waves/EU budget the allocator hit
//    pair-alignment fragmentation and spilled instead of growing past 40 VGPR.
//    Cap 128 gives slack; 4 waves/SIMD is plenty for a VALU-issue-bound body.
//  - Everything else identical to R6 (packed v2f math, product state, partial
//    rings, deferred-CNOT column swaps, measurement-absorbed final ring).

namespace {

constexpr int OUT_HW = 63;
constexpr int PPB = 4;                                  // waves (patches) per block
constexpr int N_PATCH_TOTAL = 8 * OUT_HW * OUT_HW;      // 31752 == 7938 * 4

typedef float v2f __attribute__((ext_vector_type(2)));

__device__ __forceinline__ v2f swap2(v2f x) { return (v2f){x.y, x.x}; }

// complex multiply c*x as packed ops: {c.r,c.r}*x + {-c.i,c.i}*swap(x)
__device__ __forceinline__ v2f cmul2(v2f c, v2f x) {
    return (v2f){c.x, c.x} * x + (v2f){-c.y, c.y} * swap2(x);
}
// acc += c*x
__device__ __forceinline__ v2f cmac(v2f acc, v2f c, v2f x) {
    acc += (v2f){c.x, c.x} * x;
    acc += (v2f){-c.y, c.y} * swap2(x);
    return acc;
}

__device__ __forceinline__ float bperm1(int addr_bytes, float v) {
    return __int_as_float(__builtin_amdgcn_ds_bpermute(addr_bytes, __float_as_int(v)));
}
__device__ __forceinline__ v2f bperm2(int addr_bytes, v2f v) {
    v2f r;
    r.x = bperm1(addr_bytes, v.x);
    r.y = bperm1(addr_bytes, v.y);
    return r;
}

template<int M>
__device__ __forceinline__ float shflx1(float v, int lane) {
    if constexpr (M < 32)
        return __int_as_float(__builtin_amdgcn_ds_swizzle(__float_as_int(v),
                                                          0x1F | (M << 10)));
    else
        return bperm1((lane << 2) ^ 128, v);
}
template<int M>
__device__ __forceinline__ v2f shflx2(v2f v, int lane) {
    v2f r;
    r.x = shflx1<M>(v.x, lane);
    r.y = shflx1<M>(v.y, lane);
    return r;
}

// General 2x2 unitary on qubit Q; u** are complex pairs (may be per-lane).
template<int Q>
__device__ __forceinline__ void gate1q(v2f (&a)[8], int lane,
                                       v2f u00, v2f u01, v2f u10, v2f u11)
{
    if constexpr (Q < 3) {
        constexpr int qm = 1 << Q;
        #pragma unroll
        for (int r = 0; r < 8; ++r) {
            if (!(r & qm)) {
                const int r1 = r | qm;
                const v2f x = a[r], y = a[r1];
                a[r]  = cmac(cmul2(u00, x), u01, y);
                a[r1] = cmac(cmul2(u10, x), u11, y);
            }
        }
    } else {
        constexpr int lm = 1 << (Q - 3);
        const bool bit = ((lane >> (Q - 3)) & 1) != 0;
        const v2f cs = bit ? u11 : u00;   // self coefficient
        const v2f cp = bit ? u10 : u01;   // partner coefficient
        #pragma unroll
        for (int r = 0; r < 8; ++r) {
            const v2f b = shflx2<lm>(a[r], lane);
            a[r] = cmac(cmul2(cs, a[r]), cp, b);
        }
    }
}

// Reg-reg CNOT (pure rename).
template<int C, int T>
__device__ __forceinline__ void cnot(v2f (&a)[8])
{
    static_assert(C < 3 && T < 3, "only reg-reg CNOTs instantiated");
    constexpr int cm = 1 << C, tm = 1 << T;
    #pragma unroll
    for (int r = 0; r < 8; ++r) {
        if ((r & cm) && !(r & tm)) {
            const int r1 = r | tm;
            const v2f t = a[r];
            a[r] = a[r1];
            a[r1] = t;
        }
    }
}

// Ring r=1 minus trailing cnot(8,0) (deferred as column swap):
// (0,1)(1,2) renames; (2,3)..(7,8) -> src_lane = lane ^ ((lane&31)<<1) ^ bit2(reg)
__device__ __forceinline__ void ring1_partial(v2f (&a)[8], int lane)
{
    cnot<0,1>(a);
    cnot<1,2>(a);
    const int sA = (lane ^ ((lane & 31) << 1)) << 2;
    const int sB = sA ^ 4;
    #pragma unroll
    for (int r = 0; r < 8; ++r)
        a[r] = bperm2((r & 4) ? sB : sA, a[r]);
}

// Ring r=2 minus trailing cnot(7,0),cnot(8,1) (deferred):
// (0,2) rename; (1,3)..(6,8) -> src_lane = lane ^ ((lane&15)<<2) ^ bit1 ^ bit2<<1
__device__ __forceinline__ void ring2_partial(v2f (&a)[8], int lane)
{
    cnot<0,2>(a);
    const int s0 = (lane ^ ((lane & 15) << 2)) << 2;
    #pragma unroll
    for (int r = 0; r < 8; ++r) {
        const int ad = s0 ^ (((r >> 1) & 1) << 2) ^ (((r >> 2) & 1) << 3);
        a[r] = bperm2(ad, a[r]);
    }
}

// Precompute the 18 Rot matrices (weights shared across all patches).
// rot[(l*9+q)*8 + {0..7}] = u00.re,u00.im,u01.re,u01.im,u10.re,u10.im,u11.re,u11.im
__global__ void rot_precomp_kernel(const float* __restrict__ w, float* __restrict__ rot)
{
    const int i = threadIdx.x;
    if (i >= 18) return;
    const float phi = w[i*3 + 0], theta = w[i*3 + 1], omega = w[i*3 + 2];
    const float ct = cosf(0.5f * theta), st = sinf(0.5f * theta);
    const float apo = 0.5f * (phi + omega), amo = 0.5f * (phi - omega);
    const float ca = cosf(apo), sa = sinf(apo);
    const float cm = cosf(amo), sm = sinf(amo);
    float* m = rot + i * 8;
    m[0] =  ca * ct; m[1] = -sa * ct;   // u00
    m[2] = -cm * st; m[3] = -sm * st;   // u01
    m[4] =  cm * st; m[5] = -sm * st;   // u10
    m[6] =  ca * ct; m[7] =  sa * ct;   // u11
}

#define APPLY_ROT(q) { const v2f* M = (const v2f*)(m + 8*(q)); \
    gate1q<q>(a, lane, M[0], M[1], M[2], M[3]); }

// Rot with a deferred CNOT absorbed: columns swapped on lanes where sw is set.
#define APPLY_ROT_SW(q, sw) { const v2f* M = (const v2f*)(m + 8*(q)); \
    const v2f w00 = (sw) ? M[1] : M[0]; \
    const v2f w01 = (sw) ? M[0] : M[1]; \
    const v2f w10 = (sw) ? M[3] : M[2]; \
    const v2f w11 = (sw) ? M[2] : M[3]; \
    gate1q<q>(a, lane, w00, w01, w10, w11); }

// sign-apply: v * (-1)^par  (par in {0,1})
__device__ __forceinline__ float sgn_apply(float v, int par) {
    return __int_as_float(__float_as_int(v) ^ (par << 31));
}

__global__ __launch_bounds__(PPB * 64, 4) void qconv_kernel(
    const float* __restrict__ x,      // (8, 1, 128, 128)
    const float* __restrict__ rot,    // (2, 9, 8) precomputed Rot matrices
    float* __restrict__ out)          // (8, 9, 63, 63)
{
    const int lane  = threadIdx.x & 63;
    const int wv    = threadIdx.x >> 6;
    const int patch = blockIdx.x * PPB + wv;
    if (patch >= N_PATCH_TOTAL) return;          // wave-uniform (never taken)

    const int b   = patch / (OUT_HW * OUT_HW);
    const int rem = patch - b * (OUT_HW * OUT_HW);
    const int oy  = rem / OUT_HW;
    const int ox  = rem - oy * OUT_HW;

    const float* xp = x + b * 16384 + (oy * 2) * 128 + (ox * 2);

    // ---- Product state after RX encode + Rot(l=0):
    // (alpha,beta) = first column of Rot(l0,q)*RX(a_q):
    //   alpha = {c,c}*u00 + {s,-s}*swap(u01)
    //   beta  = {c,c}*u10 + {s,-s}*swap(u11)
    v2f a[8];
    {
        v2f L = (v2f){1.0f, 0.0f};               // lane factor (qubits 3..8)
        #pragma unroll
        for (int q = 3; q < 9; ++q) {
            const float ang = xp[(q / 3) * 128 + (q % 3)];
            float s, c;
            __sincosf(0.5f * ang, &s, &c);
            const v2f* M = (const v2f*)(rot + 8 * q);
            const v2f alpha = (v2f){c, c} * M[0] + (v2f){s, -s} * swap2(M[1]);
            const v2f beta  = (v2f){c, c} * M[2] + (v2f){s, -s} * swap2(M[3]);
            const bool bit = ((lane >> (q - 3)) & 1) != 0;
            const v2f f = bit ? beta : alpha;
            L = cmul2(L, f);
        }
        v2f al[3], be[3];
        #pragma unroll
        for (int q = 0; q < 3; ++q) {
            const float ang = xp[(q / 3) * 128 + (q % 3)];
            float s, c;
            __sincosf(0.5f * ang, &s, &c);
            const v2f* M = (const v2f*)(rot + 8 * q);
            al[q] = (v2f){c, c} * M[0] + (v2f){s, -s} * swap2(M[1]);
            be[q] = (v2f){c, c} * M[2] + (v2f){s, -s} * swap2(M[3]);
        }
        v2f c01[4];
        #pragma unroll
        for (int j = 0; j < 4; ++j) {
            const v2f f0 = (j & 1) ? be[0] : al[0];
            const v2f f1 = (j & 2) ? be[1] : al[1];
            c01[j] = cmul2(f0, f1);
        }
        #pragma unroll
        for (int r = 0; r < 8; ++r) {
            const v2f f2 = (r & 4) ? be[2] : al[2];
            const v2f g = cmul2(c01[r & 3], f2);
            a[r] = cmul2(g, L);
        }
    }

    const bool b4 = ((lane >> 4) & 1) != 0;   // amp-index bit 7
    const bool b5 = ((lane >> 5) & 1) != 0;   // amp-index bit 8

    ring1_partial(a, lane);                    // cnot(8,0) deferred into L2 q0
    {   // Layer 2: Rot(l=1); q0 absorbs CNOT(8,0) (col swap on b5)
        const float* m = rot + 72;
        APPLY_ROT_SW(0, b5)
        APPLY_ROT(1) APPLY_ROT(2) APPLY_ROT(3) APPLY_ROT(4)
        APPLY_ROT(5) APPLY_ROT(6) APPLY_ROT(7) APPLY_ROT(8)
        ring2_partial(a, lane);                // cnot(7,0),(8,1) deferred into L3
    }
    {   // Layer 3: Rot(l=0); q0 absorbs CNOT(7,0) (b4), q1 absorbs CNOT(8,1) (b5)
        const float* m = rot;
        APPLY_ROT_SW(0, b4)
        APPLY_ROT_SW(1, b5)
        APPLY_ROT(2) APPLY_ROT(3) APPLY_ROT(4)
        APPLY_ROT(5) APPLY_ROT(6) APPLY_ROT(7) APPLY_ROT(8)
        ring1_partial(a, lane);                // cnot(8,0) deferred into L4 q0
    }
    {   // Layer 4: Rot(l=1); q0 absorbs CNOT(8,0) (b5). Final ring2 absorbed
        // into measurement masks below.
        const float* m = rot + 72;
        APPLY_ROT_SW(0, b5)
        APPLY_ROT(1) APPLY_ROT(2) APPLY_ROT(3) APPLY_ROT(4)
        APPLY_ROT(5) APPLY_ROT(6) APPLY_ROT(7) APPLY_ROT(8)
    }

    // ---- Measurement with final ring2 absorbed:
    // e_q = sum_p (-1)^{parity(p & w_q)} |amp_p|^2,
    // w = {0x0AB,0x157,0x005,0x00A,0x015,0x02A,0x055,0x0AA,0x155}
    float p[8];
    #pragma unroll
    for (int r = 0; r < 8; ++r) p[r] = a[r].x * a[r].x + a[r].y * a[r].y;

    const float S3 = (p[0]+p[3]+p[4]+p[7]) - (p[1]+p[2]+p[5]+p[6]);
    const float S7 = (p[0]+p[3]+p[5]+p[6]) - (p[1]+p[2]+p[4]+p[7]);
    const float S5 = (p[0]+p[2]+p[5]+p[7]) - (p[1]+p[3]+p[4]+p[6]);
    const float S2 = (p[0]+p[1]+p[4]+p[5]) - (p[2]+p[3]+p[6]+p[7]);

    const int c0 = lane & 1, c1 = (lane >> 1) & 1, c2 = (lane >> 2) & 1;
    const int c3 = (lane >> 3) & 1, c4 = (lane >> 4) & 1, c5 = (lane >> 5) & 1;
    const int p05 = c0 ^ c2, p0A = c1 ^ c3;
    const int p15 = p05 ^ c4, p2A = p0A ^ c5;

    float e[9];
    e[0] = sgn_apply(S3, p15);   // w0 = 0x0AB: reg 3, lane 0x15
    e[1] = sgn_apply(S7, p2A);   // w1 = 0x157: reg 7, lane 0x2A
    e[2] = S5;                   // w2 = 0x005: reg 5
    e[3] = sgn_apply(S2, c0);    // w3 = 0x00A: reg 2, lane 1
    e[4] = sgn_apply(S5, c1);    // w4 = 0x015: reg 5, lane 2
    e[5] = sgn_apply(S2, p05);   // w5 = 0x02A: reg 2, lane 5
    e[6] = sgn_apply(S5, p0A);   // w6 = 0x055: reg 5, lane 0xA
    e[7] = sgn_apply(S2, p15);   // w7 = 0x0AA: reg 2, lane 0x15
    e[8] = sgn_apply(S5, p2A);   // w8 = 0x155: reg 5, lane 0x2A

    // Butterfly reduce across the 64 lanes
    #pragma unroll
    for (int q = 0; q < 9; ++q) e[q] += shflx1<1>(e[q], lane);
    #pragma unroll
    for (int q = 0; q < 9; ++q) e[q] += shflx1<2>(e[q], lane);
    #pragma unroll
    for (int q = 0; q < 9; ++q) e[q] += shflx1<4>(e[q], lane);
    #pragma unroll
    for (int q = 0; q < 9; ++q) e[q] += shflx1<8>(e[q], lane);
    #pragma unroll
    for (int q = 0; q < 9; ++q) e[q] += shflx1<16>(e[q], lane);
    #pragma unroll
    for (int q = 0; q < 9; ++q) e[q] += shflx1<32>(e[q], lane);

    // lanes 0..8 each store one channel (single predicated store)
    float v = e[0];
    v = (lane == 1) ? e[1] : v;
    v = (lane == 2) ? e[2] : v;
    v = (lane == 3) ? e[3] : v;
    v = (lane == 4) ? e[4] : v;
    v = (lane == 5) ? e[5] : v;
    v = (lane == 6) ? e[6] : v;
    v = (lane == 7) ? e[7] : v;
    v = (lane == 8) ? e[8] : v;
    if (lane < 9) {
        out[(b * 9 + lane) * (OUT_HW * OUT_HW) + oy * OUT_HW + ox] = v;
    }
}

} // anonymous namespace

extern "C" void kernel_launch(void* const* d_in, const int* in_sizes, int n_in,
                              void* d_out, int out_size, void* d_ws, size_t ws_size,
                              hipStream_t stream)
{
    const float* x = (const float*)d_in[0];   // (8,1,128,128) float32
    const float* w = (const float*)d_in[1];   // (2,9,3) float32
    float* rot = (float*)d_ws;                // 144 floats scratch
    float* out = (float*)d_out;               // (8,9,63,63) float32

    rot_precomp_kernel<<<1, 64, 0, stream>>>(w, rot);
    qconv_kernel<<<N_PATCH_TOTAL / PPB, PPB * 64, 0, stream>>>(x, rot, out);
}

// Round 8
// 153.301 us; speedup vs baseline: 1.0711x; 1.0386x over previous
//
#include <hip/hip_runtime.h>

// Quanvolution: 8x1x128x128 input, K=3, STRIDE=2 -> 63x63 patches per image,
// 9-qubit statevector sim per patch, output (8, 9, 63, 63) PauliZ expvals.
//
// Layout: one wave (64 lanes) simulates TWO patches (R8). Per patch: 512
// amplitudes -> 8 complex per lane. Amplitude index bits: [2:0] = register
// slot r, [8:3] = lane id.
//
// R8 changes vs R7 (packed v2f, 120 us steady; R5 scalar was 110 us):
//  - Back to scalar fp32 math (R6/R7 showed v_pk_fma_f32 mostly didn't form;
//    packed state cost occupancy and gained nothing).
//  - TWO patches per wave, interleaved: independent dependency chains fill
//    the ds_swizzle->lgkmcnt->FMA stall bubbles that kept both R5 and R7 at
//    ~2x the pure-issue time. Total per-CU VALU/DS work unchanged.
//  - Rot coefficients are wave-uniform and shared by both in-flight patches.

namespace {

constexpr int OUT_HW = 63;
constexpr int PPB = 4;                                   // waves per block
constexpr int N_PATCH_TOTAL = 8 * OUT_HW * OUT_HW;       // 31752 == 3969*4*2
constexpr int N_BLOCKS = N_PATCH_TOTAL / (PPB * 2);      // 3969

__device__ __forceinline__ float bperm1(int addr_bytes, float v) {
    return __int_as_float(__builtin_amdgcn_ds_bpermute(addr_bytes, __float_as_int(v)));
}

template<int M>
__device__ __forceinline__ float shflx1(float v, int lane) {
    if constexpr (M < 32)
        return __int_as_float(__builtin_amdgcn_ds_swizzle(__float_as_int(v),
                                                          0x1F | (M << 10)));
    else
        return bperm1((lane << 2) ^ 128, v);
}

// General 2x2 unitary on qubit Q applied to BOTH patches' states.
// Coefficients are wave-uniform (possibly per-lane column-swapped) and shared.
template<int Q>
__device__ __forceinline__ void gate1q_dual(
    float (&ar0)[8], float (&ai0)[8], float (&ar1)[8], float (&ai1)[8], int lane,
    float u00r, float u00i, float u01r, float u01i,
    float u10r, float u10i, float u11r, float u11i)
{
    if constexpr (Q < 3) {
        constexpr int qm = 1 << Q;
        #pragma unroll
        for (int r = 0; r < 8; ++r) {
            if (!(r & qm)) {
                const int r1 = r | qm;
                {   const float xr = ar0[r],  xi = ai0[r];
                    const float yr = ar0[r1], yi = ai0[r1];
                    ar0[r]  = u00r*xr - u00i*xi + u01r*yr - u01i*yi;
                    ai0[r]  = u00r*xi + u00i*xr + u01r*yi + u01i*yr;
                    ar0[r1] = u10r*xr - u10i*xi + u11r*yr - u11i*yi;
                    ai0[r1] = u10r*xi + u10i*xr + u11r*yi + u11i*yr; }
                {   const float xr = ar1[r],  xi = ai1[r];
                    const float yr = ar1[r1], yi = ai1[r1];
                    ar1[r]  = u00r*xr - u00i*xi + u01r*yr - u01i*yi;
                    ai1[r]  = u00r*xi + u00i*xr + u01r*yi + u01i*yr;
                    ar1[r1] = u10r*xr - u10i*xi + u11r*yr - u11i*yi;
                    ai1[r1] = u10r*xi + u10i*xr + u11r*yi + u11i*yr; }
            }
        }
    } else {
        constexpr int lm = 1 << (Q - 3);
        const int bit = (lane >> (Q - 3)) & 1;
        const float csr = bit ? u11r : u00r;
        const float csi = bit ? u11i : u00i;
        const float cpr = bit ? u10r : u01r;
        const float cpi = bit ? u10i : u01i;
        #pragma unroll
        for (int r = 0; r < 8; ++r) {
            const float br0 = shflx1<lm>(ar0[r], lane);
            const float bi0 = shflx1<lm>(ai0[r], lane);
            const float br1 = shflx1<lm>(ar1[r], lane);
            const float bi1 = shflx1<lm>(ai1[r], lane);
            const float nr0 = csr*ar0[r] - csi*ai0[r] + cpr*br0 - cpi*bi0;
            const float ni0 = csr*ai0[r] + csi*ar0[r] + cpr*bi0 + cpi*br0;
            const float nr1 = csr*ar1[r] - csi*ai1[r] + cpr*br1 - cpi*bi1;
            const float ni1 = csr*ai1[r] + csi*ar1[r] + cpr*bi1 + cpi*br1;
            ar0[r] = nr0; ai0[r] = ni0;
            ar1[r] = nr1; ai1[r] = ni1;
        }
    }
}

// Reg-reg CNOT (pure rename), both patches.
template<int C, int T>
__device__ __forceinline__ void cnot_dual(
    float (&ar0)[8], float (&ai0)[8], float (&ar1)[8], float (&ai1)[8])
{
    static_assert(C < 3 && T < 3, "only reg-reg CNOTs instantiated");
    constexpr int cm = 1 << C, tm = 1 << T;
    #pragma unroll
    for (int r = 0; r < 8; ++r) {
        if ((r & cm) && !(r & tm)) {
            const int r1 = r | tm;
            float t;
            t = ar0[r]; ar0[r] = ar0[r1]; ar0[r1] = t;
            t = ai0[r]; ai0[r] = ai0[r1]; ai0[r1] = t;
            t = ar1[r]; ar1[r] = ar1[r1]; ar1[r1] = t;
            t = ai1[r]; ai1[r] = ai1[r1]; ai1[r1] = t;
        }
    }
}

// Ring r=1 minus trailing cnot(8,0) (deferred as column swap):
// (0,1)(1,2) renames; (2,3)..(7,8) -> src_lane = lane ^ ((lane&31)<<1) ^ bit2(reg)
__device__ __forceinline__ void ring1_partial_dual(
    float (&ar0)[8], float (&ai0)[8], float (&ar1)[8], float (&ai1)[8], int lane)
{
    cnot_dual<0,1>(ar0, ai0, ar1, ai1);
    cnot_dual<1,2>(ar0, ai0, ar1, ai1);
    const int sA = (lane ^ ((lane & 31) << 1)) << 2;
    const int sB = sA ^ 4;
    #pragma unroll
    for (int r = 0; r < 8; ++r) {
        const int a = (r & 4) ? sB : sA;
        ar0[r] = bperm1(a, ar0[r]);
        ai0[r] = bperm1(a, ai0[r]);
        ar1[r] = bperm1(a, ar1[r]);
        ai1[r] = bperm1(a, ai1[r]);
    }
}

// Ring r=2 minus trailing cnot(7,0),cnot(8,1) (deferred):
// (0,2) rename; (1,3)..(6,8) -> src_lane = lane ^ ((lane&15)<<2) ^ bit1 ^ bit2<<1
__device__ __forceinline__ void ring2_partial_dual(
    float (&ar0)[8], float (&ai0)[8], float (&ar1)[8], float (&ai1)[8], int lane)
{
    cnot_dual<0,2>(ar0, ai0, ar1, ai1);
    const int s0 = (lane ^ ((lane & 15) << 2)) << 2;
    #pragma unroll
    for (int r = 0; r < 8; ++r) {
        const int a = s0 ^ (((r >> 1) & 1) << 2) ^ (((r >> 2) & 1) << 3);
        ar0[r] = bperm1(a, ar0[r]);
        ai0[r] = bperm1(a, ai0[r]);
        ar1[r] = bperm1(a, ar1[r]);
        ai1[r] = bperm1(a, ai1[r]);
    }
}

// Precompute the 18 Rot matrices (weights shared across all patches).
// rot[(l*9+q)*8 + {0..7}] = u00.re,u00.im,u01.re,u01.im,u10.re,u10.im,u11.re,u11.im
__global__ void rot_precomp_kernel(const float* __restrict__ w, float* __restrict__ rot)
{
    const int i = threadIdx.x;
    if (i >= 18) return;
    const float phi = w[i*3 + 0], theta = w[i*3 + 1], omega = w[i*3 + 2];
    const float ct = cosf(0.5f * theta), st = sinf(0.5f * theta);
    const float apo = 0.5f * (phi + omega), amo = 0.5f * (phi - omega);
    const float ca = cosf(apo), sa = sinf(apo);
    const float cm = cosf(amo), sm = sinf(amo);
    float* m = rot + i * 8;
    m[0] =  ca * ct; m[1] = -sa * ct;   // u00
    m[2] = -cm * st; m[3] = -sm * st;   // u01
    m[4] =  cm * st; m[5] = -sm * st;   // u10
    m[6] =  ca * ct; m[7] =  sa * ct;   // u11
}

#define APPLY_ROT_D(q) gate1q_dual<q>(ar0,ai0,ar1,ai1,lane, \
    m[8*(q)+0], m[8*(q)+1], m[8*(q)+2], m[8*(q)+3], \
    m[8*(q)+4], m[8*(q)+5], m[8*(q)+6], m[8*(q)+7]);

// Rot with a deferred CNOT absorbed: columns swapped on lanes where sw is set.
#define APPLY_ROT_SW_D(q, sw) { \
    const float* R = m + 8*(q); \
    const float v00r = (sw) ? R[2] : R[0], v00i = (sw) ? R[3] : R[1]; \
    const float v01r = (sw) ? R[0] : R[2], v01i = (sw) ? R[1] : R[3]; \
    const float v10r = (sw) ? R[6] : R[4], v10i = (sw) ? R[7] : R[5]; \
    const float v11r = (sw) ? R[4] : R[6], v11i = (sw) ? R[5] : R[7]; \
    gate1q_dual<q>(ar0,ai0,ar1,ai1,lane, v00r,v00i,v01r,v01i,v10r,v10i,v11r,v11i); }

// sign-apply: v * (-1)^par  (par in {0,1})
__device__ __forceinline__ float sgn_apply(float v, int par) {
    return __int_as_float(__float_as_int(v) ^ (par << 31));
}

// Build product state for one patch (after RX encode + Rot(l=0)).
__device__ __forceinline__ void build_state(
    const float* __restrict__ xp, const float* __restrict__ rot, int lane,
    float (&ar)[8], float (&ai)[8])
{
    float Lr = 1.0f, Li = 0.0f;              // lane factor (qubits 3..8)
    #pragma unroll
    for (int q = 3; q < 9; ++q) {
        const float a = xp[(q / 3) * 128 + (q % 3)];
        float s, c;
        __sincosf(0.5f * a, &s, &c);
        const float* R = rot + 8 * q;
        const float alr = c*R[0] + s*R[3], ali = c*R[1] - s*R[2];
        const float ber = c*R[4] + s*R[7], bei = c*R[5] - s*R[6];
        const int bit = (lane >> (q - 3)) & 1;
        const float fr = bit ? ber : alr;
        const float fi = bit ? bei : ali;
        const float nr = Lr*fr - Li*fi;
        const float ni = Lr*fi + Li*fr;
        Lr = nr; Li = ni;
    }
    float alr[3], ali_[3], ber[3], bei[3];
    #pragma unroll
    for (int q = 0; q < 3; ++q) {
        const float a = xp[(q / 3) * 128 + (q % 3)];
        float s, c;
        __sincosf(0.5f * a, &s, &c);
        const float* R = rot + 8 * q;
        alr[q] = c*R[0] + s*R[3]; ali_[q] = c*R[1] - s*R[2];
        ber[q] = c*R[4] + s*R[7]; bei[q] = c*R[5] - s*R[6];
    }
    float c01r[4], c01i[4];
    #pragma unroll
    for (int j = 0; j < 4; ++j) {
        const float f0r = (j & 1) ? ber[0] : alr[0];
        const float f0i = (j & 1) ? bei[0] : ali_[0];
        const float f1r = (j & 2) ? ber[1] : alr[1];
        const float f1i = (j & 2) ? bei[1] : ali_[1];
        c01r[j] = f0r*f1r - f0i*f1i;
        c01i[j] = f0r*f1i + f0i*f1r;
    }
    #pragma unroll
    for (int r = 0; r < 8; ++r) {
        const float f2r = (r & 4) ? ber[2] : alr[2];
        const float f2i = (r & 4) ? bei[2] : ali_[2];
        const float gr = c01r[r & 3]*f2r - c01i[r & 3]*f2i;
        const float gi = c01r[r & 3]*f2i + c01i[r & 3]*f2r;
        ar[r] = gr*Lr - gi*Li;
        ai[r] = gr*Li + gi*Lr;
    }
}

// Measurement with final ring2 absorbed (masks w_q), one patch.
__device__ __forceinline__ void measure(
    const float (&ar)[8], const float (&ai)[8], int lane, float (&e)[9])
{
    float p[8];
    #pragma unroll
    for (int r = 0; r < 8; ++r) p[r] = ar[r]*ar[r] + ai[r]*ai[r];

    const float S3 = (p[0]+p[3]+p[4]+p[7]) - (p[1]+p[2]+p[5]+p[6]);
    const float S7 = (p[0]+p[3]+p[5]+p[6]) - (p[1]+p[2]+p[4]+p[7]);
    const float S5 = (p[0]+p[2]+p[5]+p[7]) - (p[1]+p[3]+p[4]+p[6]);
    const float S2 = (p[0]+p[1]+p[4]+p[5]) - (p[2]+p[3]+p[6]+p[7]);

    const int c0 = lane & 1, c1 = (lane >> 1) & 1, c2 = (lane >> 2) & 1;
    const int c3 = (lane >> 3) & 1, c4 = (lane >> 4) & 1, c5 = (lane >> 5) & 1;
    const int p05 = c0 ^ c2, p0A = c1 ^ c3;
    const int p15 = p05 ^ c4, p2A = p0A ^ c5;

    e[0] = sgn_apply(S3, p15);   // w0 = 0x0AB
    e[1] = sgn_apply(S7, p2A);   // w1 = 0x157
    e[2] = S5;                   // w2 = 0x005
    e[3] = sgn_apply(S2, c0);    // w3 = 0x00A
    e[4] = sgn_apply(S5, c1);    // w4 = 0x015
    e[5] = sgn_apply(S2, p05);   // w5 = 0x02A
    e[6] = sgn_apply(S5, p0A);   // w6 = 0x055
    e[7] = sgn_apply(S2, p15);   // w7 = 0x0AA
    e[8] = sgn_apply(S5, p2A);   // w8 = 0x155
}

__global__ __launch_bounds__(PPB * 64, 4) void qconv_kernel(
    const float* __restrict__ x,      // (8, 1, 128, 128)
    const float* __restrict__ rot,    // (2, 9, 8) precomputed Rot matrices
    float* __restrict__ out)          // (8, 9, 63, 63)
{
    const int lane = threadIdx.x & 63;
    const int wv   = threadIdx.x >> 6;
    const int wave_id = blockIdx.x * PPB + wv;
    const int patch0 = wave_id * 2;
    const int patch1 = patch0 + 1;

    const int b0   = patch0 / (OUT_HW * OUT_HW);
    const int rem0 = patch0 - b0 * (OUT_HW * OUT_HW);
    const int oy0  = rem0 / OUT_HW;
    const int ox0  = rem0 - oy0 * OUT_HW;
    const int b1   = patch1 / (OUT_HW * OUT_HW);
    const int rem1 = patch1 - b1 * (OUT_HW * OUT_HW);
    const int oy1  = rem1 / OUT_HW;
    const int ox1  = rem1 - oy1 * OUT_HW;

    const float* xp0 = x + b0 * 16384 + (oy0 * 2) * 128 + (ox0 * 2);
    const float* xp1 = x + b1 * 16384 + (oy1 * 2) * 128 + (ox1 * 2);

    float ar0[8], ai0[8], ar1[8], ai1[8];
    build_state(xp0, rot, lane, ar0, ai0);
    build_state(xp1, rot, lane, ar1, ai1);

    const bool b4 = ((lane >> 4) & 1) != 0;   // amp-index bit 7
    const bool b5 = ((lane >> 5) & 1) != 0;   // amp-index bit 8

    ring1_partial_dual(ar0, ai0, ar1, ai1, lane);   // cnot(8,0) -> L2 q0
    {   // Layer 2: Rot(l=1); q0 absorbs CNOT(8,0) (col swap on b5)
        const float* m = rot + 72;
        APPLY_ROT_SW_D(0, b5)
        APPLY_ROT_D(1) APPLY_ROT_D(2) APPLY_ROT_D(3) APPLY_ROT_D(4)
        APPLY_ROT_D(5) APPLY_ROT_D(6) APPLY_ROT_D(7) APPLY_ROT_D(8)
        ring2_partial_dual(ar0, ai0, ar1, ai1, lane);  // (7,0),(8,1) -> L3
    }
    {   // Layer 3: Rot(l=0); q0 absorbs CNOT(7,0) (b4), q1 absorbs CNOT(8,1) (b5)
        const float* m = rot;
        APPLY_ROT_SW_D(0, b4)
        APPLY_ROT_SW_D(1, b5)
        APPLY_ROT_D(2) APPLY_ROT_D(3) APPLY_ROT_D(4)
        APPLY_ROT_D(5) APPLY_ROT_D(6) APPLY_ROT_D(7) APPLY_ROT_D(8)
        ring1_partial_dual(ar0, ai0, ar1, ai1, lane);  // cnot(8,0) -> L4 q0
    }
    {   // Layer 4: Rot(l=1); q0 absorbs CNOT(8,0) (b5). Final ring2 absorbed
        // into measurement masks.
        const float* m = rot + 72;
        APPLY_ROT_SW_D(0, b5)
        APPLY_ROT_D(1) APPLY_ROT_D(2) APPLY_ROT_D(3) APPLY_ROT_D(4)
        APPLY_ROT_D(5) APPLY_ROT_D(6) APPLY_ROT_D(7) APPLY_ROT_D(8)
    }

    float e0[9], e1[9];
    measure(ar0, ai0, lane, e0);
    measure(ar1, ai1, lane, e1);

    // Butterfly reduce both patches (interleaved for ILP)
    #pragma unroll
    for (int q = 0; q < 9; ++q) { e0[q] += shflx1<1>(e0[q], lane);
                                  e1[q] += shflx1<1>(e1[q], lane); }
    #pragma unroll
    for (int q = 0; q < 9; ++q) { e0[q] += shflx1<2>(e0[q], lane);
                                  e1[q] += shflx1<2>(e1[q], lane); }
    #pragma unroll
    for (int q = 0; q < 9; ++q) { e0[q] += shflx1<4>(e0[q], lane);
                                  e1[q] += shflx1<4>(e1[q], lane); }
    #pragma unroll
    for (int q = 0; q < 9; ++q) { e0[q] += shflx1<8>(e0[q], lane);
                                  e1[q] += shflx1<8>(e1[q], lane); }
    #pragma unroll
    for (int q = 0; q < 9; ++q) { e0[q] += shflx1<16>(e0[q], lane);
                                  e1[q] += shflx1<16>(e1[q], lane); }
    #pragma unroll
    for (int q = 0; q < 9; ++q) { e0[q] += shflx1<32>(e0[q], lane);
                                  e1[q] += shflx1<32>(e1[q], lane); }

    // lanes 0..8 store patch0's channels; lanes 16..24 store patch1's
    float v0 = e0[0];
    v0 = (lane == 1) ? e0[1] : v0;
    v0 = (lane == 2) ? e0[2] : v0;
    v0 = (lane == 3) ? e0[3] : v0;
    v0 = (lane == 4) ? e0[4] : v0;
    v0 = (lane == 5) ? e0[5] : v0;
    v0 = (lane == 6) ? e0[6] : v0;
    v0 = (lane == 7) ? e0[7] : v0;
    v0 = (lane == 8) ? e0[8] : v0;
    const int l16 = lane - 16;
    float v1 = e1[0];
    v1 = (l16 == 1) ? e1[1] : v1;
    v1 = (l16 == 2) ? e1[2] : v1;
    v1 = (l16 == 3) ? e1[3] : v1;
    v1 = (l16 == 4) ? e1[4] : v1;
    v1 = (l16 == 5) ? e1[5] : v1;
    v1 = (l16 == 6) ? e1[6] : v1;
    v1 = (l16 == 7) ? e1[7] : v1;
    v1 = (l16 == 8) ? e1[8] : v1;
    if (lane < 9)
        out[(b0 * 9 + lane) * (OUT_HW * OUT_HW) + oy0 * OUT_HW + ox0] = v0;
    if (l16 >= 0 && l16 < 9)
        out[(b1 * 9 + l16) * (OUT_HW * OUT_HW) + oy1 * OUT_HW + ox1] = v1;
}

} // anonymous namespace

extern "C" void kernel_launch(void* const* d_in, const int* in_sizes, int n_in,
                              void* d_out, int out_size, void* d_ws, size_t ws_size,
                              hipStream_t stream)
{
    const float* x = (const float*)d_in[0];   // (8,1,128,128) float32
    const float* w = (const float*)d_in[1];   // (2,9,3) float32
    float* rot = (float*)d_ws;                // 144 floats scratch
    float* out = (float*)d_out;               // (8,9,63,63) float32

    rot_precomp_kernel<<<1, 64, 0, stream>>>(w, rot);
    qconv_kernel<<<N_BLOCKS, PPB * 64, 0, stream>>>(x, rot, out);
}

// Round 9
// 137.196 us; speedup vs baseline: 1.1968x; 1.1174x over previous
//
#include <hip/hip_runtime.h>

// Quanvolution: 8x1x128x128 input, K=3, STRIDE=2 -> 63x63 patches per image,
// 9-qubit statevector sim per patch, output (8, 9, 63, 63) PauliZ expvals.
//
// Layout: one wave per patch; 8 complex amps/lane. Amp index bits:
// [2:0]=reg slot, [8:3]=lane. (R8's dual-patch showed no gain -> single.)
//
// R9: Rot = RZ(omega) RY(theta) RZ(phi) factorization.
//  - RY layers are REAL 2x2 rotations: 8 FMA/pair instead of 16 (halves the
//    gate-core VALU, the measured issue-bound bottleneck).
//  - RZ diagonals conjugated through rings (diag->diag, Z_q -> Z_{mask_q}) and
//    merged: U = Y1 R1 D_C Y0 R2 D_B Y1 R1 D_A build, measured with R4's
//    verified ring2 masks; final Omega1 layer dropped (|amp|^2 kills phases).
//    D_A = R1'(Phi1)R1; D_B = R2'(Phi0)R2 * Omega1; D_C = R1'(Phi1)R1 * Omega0.
//  - Ring1 pull-back masks derived with the R4-HW-verified row-update rule
//    (cross-checked by re-deriving ring2's masks exactly):
//    v = {0x1FE,0x3,0x7,0xF,0x1F,0x3F,0x7F,0xFF,0x1FF}.
//  - D_A/B/C are weight-only -> precomputed 64x8 phasor tables (12 KB, L1-
//    resident). One diag = 8 complex muls + 8 cached loads.
//  - Skeleton (partial-ring gathers, deferred-CNOT column swaps in the q0/q1
//    gates, measurement masks, build_state) identical to verified R5.

namespace {

constexpr int OUT_HW = 63;
constexpr int PPB = 4;                                  // waves per block
constexpr int N_PATCH_TOTAL = 8 * OUT_HW * OUT_HW;      // 31752 == 7938 * 4

__device__ __forceinline__ float bperm1(int addr_bytes, float v) {
    return __int_as_float(__builtin_amdgcn_ds_bpermute(addr_bytes, __float_as_int(v)));
}

template<int M>
__device__ __forceinline__ float shflx1(float v, int lane) {
    if constexpr (M < 32)
        return __int_as_float(__builtin_amdgcn_ds_swizzle(__float_as_int(v),
                                                          0x1F | (M << 10)));
    else
        return bperm1((lane << 2) ^ 128, v);
}

// Reg-reg CNOT renames (verified R5).
template<int C, int T>
__device__ __forceinline__ void cnot(float (&ar)[8], float (&ai)[8])
{
    constexpr int cm = 1 << C, tm = 1 << T;
    #pragma unroll
    for (int r = 0; r < 8; ++r) {
        if ((r & cm) && !(r & tm)) {
            const int r1 = r | tm;
            float t;
            t = ar[r]; ar[r] = ar[r1]; ar[r1] = t;
            t = ai[r]; ai[r] = ai[r1]; ai[r1] = t;
        }
    }
}

// Ring r=1 minus trailing cnot(8,0) (deferred as col swap into next Y q0):
// (0,1)(1,2) renames; (2,3)..(7,8) -> src_lane = lane ^ ((lane&31)<<1) ^ bit2(reg)
__device__ __forceinline__ void ring1_partial(float (&ar)[8], float (&ai)[8], int lane)
{
    cnot<0,1>(ar, ai);
    cnot<1,2>(ar, ai);
    const int sA = (lane ^ ((lane & 31) << 1)) << 2;
    const int sB = sA ^ 4;
    #pragma unroll
    for (int r = 0; r < 8; ++r) {
        const int a = (r & 4) ? sB : sA;
        ar[r] = bperm1(a, ar[r]);
        ai[r] = bperm1(a, ai[r]);
    }
}

// Ring r=2 minus trailing cnot(7,0),cnot(8,1) (deferred):
// (0,2) rename; (1,3)..(6,8) -> src_lane = lane ^ ((lane&15)<<2) ^ bit1 ^ bit2<<1
__device__ __forceinline__ void ring2_partial(float (&ar)[8], float (&ai)[8], int lane)
{
    cnot<0,2>(ar, ai);
    const int s0 = (lane ^ ((lane & 15) << 2)) << 2;
    #pragma unroll
    for (int r = 0; r < 8; ++r) {
        const int a = s0 ^ (((r >> 1) & 1) << 2) ^ (((r >> 2) & 1) << 3);
        ar[r] = bperm1(a, ar[r]);
        ai[r] = bperm1(a, ai[r]);
    }
}

// ---- Precompute (weights-only): rot matrices (for build), RY (c,s) table,
// and the three merged-diag phasor tables.
// ws layout: [0..144) rot, [144..180) ytab (18 x {c,s}), [192..3264) dtab
//            dtab[((d*8 + r)*64 + lane)*2 + {re,im}], d in {A=0,B=1,C=2}.
__global__ void precomp_kernel(const float* __restrict__ w, float* __restrict__ ws)
{
    const int tid = threadIdx.x;
    float* rot  = ws;
    float* ytab = ws + 144;
    float* dtab = ws + 192;
    if (tid < 18) {
        const float phi = w[tid*3 + 0], theta = w[tid*3 + 1], omega = w[tid*3 + 2];
        const float ct = cosf(0.5f * theta), st = sinf(0.5f * theta);
        const float apo = 0.5f * (phi + omega), amo = 0.5f * (phi - omega);
        const float ca = cosf(apo), sa = sinf(apo);
        const float cm = cosf(amo), sm = sinf(amo);
        float* m = rot + tid * 8;
        m[0] =  ca * ct; m[1] = -sa * ct;   // u00
        m[2] = -cm * st; m[3] = -sm * st;   // u01
        m[4] =  cm * st; m[5] = -sm * st;   // u10
        m[6] =  ca * ct; m[7] =  sa * ct;   // u11
        ytab[tid*2 + 0] = ct;
        ytab[tid*2 + 1] = st;
    }
    if (tid < 192) {
        // ring1 pull-back masks (row-update rule, procedure verified vs ring2)
        const int vmask[9] = {0x1FE,0x003,0x007,0x00F,0x01F,0x03F,0x07F,0x0FF,0x1FF};
        // ring2 pull-back masks (HW-verified in R4/R5 measurement absorption)
        const int wmask[9] = {0x0AB,0x157,0x005,0x00A,0x015,0x02A,0x055,0x0AA,0x155};
        const int d = tid >> 6, lane = tid & 63;
        for (int r = 0; r < 8; ++r) {
            const int p = (lane << 3) | r;
            float ang = 0.f;
            for (int q = 0; q < 9; ++q) {
                if (d == 0) {            // D_A: conj(Phi_l1) through ring1
                    const float lam = -0.5f * w[(9 + q)*3 + 0];
                    ang += (__popc(p & vmask[q]) & 1) ? -lam : lam;
                } else if (d == 1) {     // D_B: conj(Phi_l0) thru ring2 + Omega_l1
                    const float lam = -0.5f * w[q*3 + 0];
                    ang += (__popc(p & wmask[q]) & 1) ? -lam : lam;
                    const float lm2 = -0.5f * w[(9 + q)*3 + 2];
                    ang += ((p >> q) & 1) ? -lm2 : lm2;
                } else {                 // D_C: conj(Phi_l1) thru ring1 + Omega_l0
                    const float lam = -0.5f * w[(9 + q)*3 + 0];
                    ang += (__popc(p & vmask[q]) & 1) ? -lam : lam;
                    const float lm2 = -0.5f * w[q*3 + 2];
                    ang += ((p >> q) & 1) ? -lm2 : lm2;
                }
            }
            dtab[((d*8 + r)*64 + lane)*2 + 0] = cosf(ang);
            dtab[((d*8 + r)*64 + lane)*2 + 1] = sinf(ang);
        }
    }
}

// Diagonal phase layer from a precomputed phasor table (8 cmul).
__device__ __forceinline__ void apply_diag(float (&ar)[8], float (&ai)[8],
                                           const float* __restrict__ tab, int lane)
{
    #pragma unroll
    for (int r = 0; r < 8; ++r) {
        const float pr = tab[(r*64 + lane)*2 + 0];
        const float pi = tab[(r*64 + lane)*2 + 1];
        const float nr = pr*ar[r] - pi*ai[r];
        const float ni = pr*ai[r] + pi*ar[r];
        ar[r] = nr; ai[r] = ni;
    }
}

// RY gate on reg qubit (mask QM). out0 = A x0 + B x1; out1 = C2 x0 + D2 x1.
template<int QM>
__device__ __forceinline__ void regY(float (&ar)[8], float (&ai)[8],
                                     float A, float B, float C2, float D2)
{
    #pragma unroll
    for (int r = 0; r < 8; ++r) {
        if (!(r & QM)) {
            const int r1 = r | QM;
            const float x0r = ar[r],  x0i = ai[r];
            const float x1r = ar[r1], x1i = ai[r1];
            ar[r]  = A*x0r  + B*x1r;   ai[r]  = A*x0i  + B*x1i;
            ar[r1] = C2*x0r + D2*x1r;  ai[r1] = C2*x0i + D2*x1i;
        }
    }
}

// RY gate on lane qubit (xor mask LM): out = c*self + sp*partner,
// sp = bit ? +s : -s (computed at call site).
template<int LM>
__device__ __forceinline__ void laneY(float (&ar)[8], float (&ai)[8], int lane,
                                      float c, float sp)
{
    #pragma unroll
    for (int r = 0; r < 8; ++r) {
        const float br = shflx1<LM>(ar[r], lane);
        const float bi = shflx1<LM>(ai[r], lane);
        ar[r] = c*ar[r] + sp*br;
        ai[r] = c*ai[r] + sp*bi;
    }
}

// Full RY layer. yt -> 9 x {c,s}. sw0/sw1: deferred-CNOT column swaps on the
// q0/q1 gates (G*CNOT == col-swapped G on ctrl lanes; verified R5 mechanism).
__device__ __forceinline__ void apply_Y(float (&ar)[8], float (&ai)[8], int lane,
                                        const float* __restrict__ yt,
                                        bool sw0, bool sw1)
{
    {   const float c = yt[0], s = yt[1];
        const float A  = sw0 ? -s : c, B  = sw0 ? c : -s;
        const float C2 = sw0 ?  c : s, D2 = sw0 ? s :  c;
        regY<1>(ar, ai, A, B, C2, D2); }
    {   const float c = yt[2], s = yt[3];
        const float A  = sw1 ? -s : c, B  = sw1 ? c : -s;
        const float C2 = sw1 ?  c : s, D2 = sw1 ? s :  c;
        regY<2>(ar, ai, A, B, C2, D2); }
    {   const float c = yt[4], s = yt[5];
        regY<4>(ar, ai, c, -s, s, c); }
    {   const float c = yt[6],  s = yt[7];
        laneY<1>(ar, ai, lane, c, (lane & 1) ? s : -s); }
    {   const float c = yt[8],  s = yt[9];
        laneY<2>(ar, ai, lane, c, ((lane >> 1) & 1) ? s : -s); }
    {   const float c = yt[10], s = yt[11];
        laneY<4>(ar, ai, lane, c, ((lane >> 2) & 1) ? s : -s); }
    {   const float c = yt[12], s = yt[13];
        laneY<8>(ar, ai, lane, c, ((lane >> 3) & 1) ? s : -s); }
    {   const float c = yt[14], s = yt[15];
        laneY<16>(ar, ai, lane, c, ((lane >> 4) & 1) ? s : -s); }
    {   const float c = yt[16], s = yt[17];
        laneY<32>(ar, ai, lane, c, ((lane >> 5) & 1) ? s : -s); }
}

// sign-apply: v * (-1)^par
__device__ __forceinline__ float sgn_apply(float v, int par) {
    return __int_as_float(__float_as_int(v) ^ (par << 31));
}

__global__ __launch_bounds__(PPB * 64, 6) void qconv_kernel(
    const float* __restrict__ x,      // (8, 1, 128, 128)
    const float* __restrict__ ws,     // precomp tables
    float* __restrict__ out)          // (8, 9, 63, 63)
{
    const float* rot  = ws;
    const float* ytab = ws + 144;
    const float* dtab = ws + 192;

    const int lane  = threadIdx.x & 63;
    const int wv    = threadIdx.x >> 6;
    const int patch = blockIdx.x * PPB + wv;
    if (patch >= N_PATCH_TOTAL) return;          // wave-uniform (never taken)

    const int b   = patch / (OUT_HW * OUT_HW);
    const int rem = patch - b * (OUT_HW * OUT_HW);
    const int oy  = rem / OUT_HW;
    const int ox  = rem - oy * OUT_HW;

    const float* xp = x + b * 16384 + (oy * 2) * 128 + (ox * 2);

    // ---- Product state after full RotL0 * RX (unchanged, verified R5):
    float ar[8], ai[8];
    {
        float Lr = 1.0f, Li = 0.0f;
        #pragma unroll
        for (int q = 3; q < 9; ++q) {
            const float a = xp[(q / 3) * 128 + (q % 3)];
            float s, c;
            __sincosf(0.5f * a, &s, &c);
            const float* R = rot + 8 * q;
            const float alr = c*R[0] + s*R[3], ali = c*R[1] - s*R[2];
            const float ber = c*R[4] + s*R[7], bei = c*R[5] - s*R[6];
            const int bit = (lane >> (q - 3)) & 1;
            const float fr = bit ? ber : alr;
            const float fi = bit ? bei : ali;
            const float nr = Lr*fr - Li*fi;
            const float ni = Lr*fi + Li*fr;
            Lr = nr; Li = ni;
        }
        float alr[3], ali_[3], ber[3], bei[3];
        #pragma unroll
        for (int q = 0; q < 3; ++q) {
            const float a = xp[(q / 3) * 128 + (q % 3)];
            float s, c;
            __sincosf(0.5f * a, &s, &c);
            const float* R = rot + 8 * q;
            alr[q] = c*R[0] + s*R[3]; ali_[q] = c*R[1] - s*R[2];
            ber[q] = c*R[4] + s*R[7]; bei[q] = c*R[5] - s*R[6];
        }
        float c01r[4], c01i[4];
        #pragma unroll
        for (int j = 0; j < 4; ++j) {
            const float f0r = (j & 1) ? ber[0] : alr[0];
            const float f0i = (j & 1) ? bei[0] : ali_[0];
            const float f1r = (j & 2) ? ber[1] : alr[1];
            const float f1i = (j & 2) ? bei[1] : ali_[1];
            c01r[j] = f0r*f1r - f0i*f1i;
            c01i[j] = f0r*f1i + f0i*f1r;
        }
        #pragma unroll
        for (int r = 0; r < 8; ++r) {
            const float f2r = (r & 4) ? ber[2] : alr[2];
            const float f2i = (r & 4) ? bei[2] : ali_[2];
            const float gr = c01r[r & 3]*f2r - c01i[r & 3]*f2i;
            const float gi = c01r[r & 3]*f2i + c01i[r & 3]*f2r;
            ar[r] = gr*Lr - gi*Li;
            ai[r] = gr*Li + gi*Lr;
        }
    }

    const bool b4 = ((lane >> 4) & 1) != 0;   // amp-index bit 7 (qubit 7)
    const bool b5 = ((lane >> 5) & 1) != 0;   // amp-index bit 8 (qubit 8)

    // U = Y1 R1 D_C Y0 R2 D_B Y1 R1 D_A |build>, measured with ring2 masks.
    apply_diag(ar, ai, dtab + 0*1024, lane);          // D_A
    ring1_partial(ar, ai, lane);                      // cnot(8,0) -> Y q0 swap
    apply_Y(ar, ai, lane, ytab + 18, b5, false);      // Y(l=1)
    apply_diag(ar, ai, dtab + 1*1024, lane);          // D_B
    ring2_partial(ar, ai, lane);                      // (7,0),(8,1) -> Y q0/q1
    apply_Y(ar, ai, lane, ytab + 0, b4, b5);          // Y(l=0)
    apply_diag(ar, ai, dtab + 2*1024, lane);          // D_C
    ring1_partial(ar, ai, lane);                      // cnot(8,0) -> Y q0 swap
    apply_Y(ar, ai, lane, ytab + 18, b5, false);      // Y(l=1)
    // final Omega(l=1) dropped (phase-invariant measurement);
    // final ring2 absorbed into the masks below (verified R4/R5).

    // ---- Measurement: e_q = sum_p (-1)^{parity(p & w_q)} |amp_p|^2
    float p[8];
    #pragma unroll
    for (int r = 0; r < 8; ++r) p[r] = ar[r]*ar[r] + ai[r]*ai[r];

    const float S3 = (p[0]+p[3]+p[4]+p[7]) - (p[1]+p[2]+p[5]+p[6]);
    const float S7 = (p[0]+p[3]+p[5]+p[6]) - (p[1]+p[2]+p[4]+p[7]);
    const float S5 = (p[0]+p[2]+p[5]+p[7]) - (p[1]+p[3]+p[4]+p[6]);
    const float S2 = (p[0]+p[1]+p[4]+p[5]) - (p[2]+p[3]+p[6]+p[7]);

    const int c0 = lane & 1, c1 = (lane >> 1) & 1, c2 = (lane >> 2) & 1;
    const int c3 = (lane >> 3) & 1, c4 = (lane >> 4) & 1, c5 = (lane >> 5) & 1;
    const int p05 = c0 ^ c2, p0A = c1 ^ c3;
    const int p15 = p05 ^ c4, p2A = p0A ^ c5;

    float e[9];
    e[0] = sgn_apply(S3, p15);   // w0 = 0x0AB
    e[1] = sgn_apply(S7, p2A);   // w1 = 0x157
    e[2] = S5;                   // w2 = 0x005
    e[3] = sgn_apply(S2, c0);    // w3 = 0x00A
    e[4] = sgn_apply(S5, c1);    // w4 = 0x015
    e[5] = sgn_apply(S2, p05);   // w5 = 0x02A
    e[6] = sgn_apply(S5, p0A);   // w6 = 0x055
    e[7] = sgn_apply(S2, p15);   // w7 = 0x0AA
    e[8] = sgn_apply(S5, p2A);   // w8 = 0x155

    #pragma unroll
    for (int q = 0; q < 9; ++q) e[q] += shflx1<1>(e[q], lane);
    #pragma unroll
    for (int q = 0; q < 9; ++q) e[q] += shflx1<2>(e[q], lane);
    #pragma unroll
    for (int q = 0; q < 9; ++q) e[q] += shflx1<4>(e[q], lane);
    #pragma unroll
    for (int q = 0; q < 9; ++q) e[q] += shflx1<8>(e[q], lane);
    #pragma unroll
    for (int q = 0; q < 9; ++q) e[q] += shflx1<16>(e[q], lane);
    #pragma unroll
    for (int q = 0; q < 9; ++q) e[q] += shflx1<32>(e[q], lane);

    float v = e[0];
    v = (lane == 1) ? e[1] : v;
    v = (lane == 2) ? e[2] : v;
    v = (lane == 3) ? e[3] : v;
    v = (lane == 4) ? e[4] : v;
    v = (lane == 5) ? e[5] : v;
    v = (lane == 6) ? e[6] : v;
    v = (lane == 7) ? e[7] : v;
    v = (lane == 8) ? e[8] : v;
    if (lane < 9) {
        out[(b * 9 + lane) * (OUT_HW * OUT_HW) + oy * OUT_HW + ox] = v;
    }
}

} // anonymous namespace

extern "C" void kernel_launch(void* const* d_in, const int* in_sizes, int n_in,
                              void* d_out, int out_size, void* d_ws, size_t ws_size,
                              hipStream_t stream)
{
    const float* x = (const float*)d_in[0];   // (8,1,128,128) float32
    const float* w = (const float*)d_in[1];   // (2,9,3) float32
    float* ws = (float*)d_ws;                 // 3264 floats scratch
    float* out = (float*)d_out;               // (8,9,63,63) float32

    precomp_kernel<<<1, 256, 0, stream>>>(w, ws);
    qconv_kernel<<<N_PATCH_TOTAL / PPB, PPB * 64, 0, stream>>>(x, ws, out);
}

// Round 11
// 114.982 us; speedup vs baseline: 1.4280x; 1.1932x over previous
//
#include <hip/hip_runtime.h>

// Quanvolution: 8x1x128x128 input, K=3, STRIDE=2 -> 63x63 patches per image,
// 9-qubit statevector sim per patch, output (8, 9, 63, 63) PauliZ expvals.
//
// Layout: one wave per patch; 8 complex amps/lane. Amp index bits:
// [2:0]=reg slot, [8:3]=lane.
//
// R11 = R10 with the cvt_pkrtz return type bit_cast fixed (compile error);
// theory unchanged:
//  - State packed as _Float16 x2 {re,im} per amp (one VGPR). CDNA4 f16 packed
//    ops are true 2x rate (v_pk_fma_f16), unlike fp32 (no packed 2x, R6/R7).
//  - One b32 shuffle moves a whole complex: DS per lane-gate 16 -> 8, rings
//    16 -> 8 bperm.
//  - RY pair update: 4 pk ops vs 8 FMA. Diag: swap + 2 pk vs 6 FMA, tables
//    pre-packed as {c,c},{-s,+s}.
//  - build_state stays fp32 (accuracy) and packs once; measurement unpacks;
//    butterfly + parity masks stay fp32.
//  - Circuit algebra unchanged from R9 (verified): build(RotL0*RX product),
//    D_A, ring1, Y1, D_B, ring2, Y0, D_C, ring1, Y1, measure w/ ring2+Omega
//    absorbed.

namespace {

constexpr int OUT_HW = 63;
constexpr int PPB = 4;                                  // waves per block
constexpr int N_PATCH_TOTAL = 8 * OUT_HW * OUT_HW;      // 31752 == 7938 * 4

typedef _Float16 h2 __attribute__((ext_vector_type(2)));

__device__ __forceinline__ int h2i(h2 v) { return __builtin_bit_cast(int, v); }
__device__ __forceinline__ h2  i2h(int v) { return __builtin_bit_cast(h2, v); }
__device__ __forceinline__ h2  swap_h2(h2 v) { return __builtin_shufflevector(v, v, 1, 0); }

__device__ __forceinline__ int bperm_i(int addr, int v) {
    return __builtin_amdgcn_ds_bpermute(addr, v);
}
template<int M>
__device__ __forceinline__ int shfl_i(int v, int lane) {
    if constexpr (M < 32)
        return __builtin_amdgcn_ds_swizzle(v, 0x1F | (M << 10));
    else
        return bperm_i((lane << 2) ^ 128, v);
}
template<int M>
__device__ __forceinline__ float shfl_f(float v, int lane) {
    return __int_as_float(shfl_i<M>(__float_as_int(v), lane));
}

// Reg-reg CNOT renames (verified R5/R9), packed state.
template<int C, int T>
__device__ __forceinline__ void cnot_h(h2 (&a)[8])
{
    constexpr int cm = 1 << C, tm = 1 << T;
    #pragma unroll
    for (int r = 0; r < 8; ++r) {
        if ((r & cm) && !(r & tm)) {
            const int r1 = r | tm;
            const h2 t = a[r]; a[r] = a[r1]; a[r1] = t;
        }
    }
}

// Ring r=1 minus trailing cnot(8,0): (0,1)(1,2) renames;
// (2,3)..(7,8) -> src_lane = lane ^ ((lane&31)<<1) ^ bit2(reg).
__device__ __forceinline__ void ring1_partial_h(h2 (&a)[8], int lane)
{
    cnot_h<0,1>(a);
    cnot_h<1,2>(a);
    const int sA = (lane ^ ((lane & 31) << 1)) << 2;
    const int sB = sA ^ 4;
    #pragma unroll
    for (int r = 0; r < 8; ++r)
        a[r] = i2h(bperm_i((r & 4) ? sB : sA, h2i(a[r])));
}

// Ring r=2 minus trailing cnot(7,0),cnot(8,1): (0,2) rename;
// (1,3)..(6,8) -> src_lane = lane ^ ((lane&15)<<2) ^ bit1 ^ bit2<<1.
__device__ __forceinline__ void ring2_partial_h(h2 (&a)[8], int lane)
{
    cnot_h<0,2>(a);
    const int s0 = (lane ^ ((lane & 15) << 2)) << 2;
    #pragma unroll
    for (int r = 0; r < 8; ++r) {
        const int ad = s0 ^ (((r >> 1) & 1) << 2) ^ (((r >> 2) & 1) << 3);
        a[r] = i2h(bperm_i(ad, h2i(a[r])));
    }
}

// Diagonal phase layer, packed table: per (r,lane): {c,c} and {-s,+s}.
__device__ __forceinline__ void apply_diag_h(h2 (&a)[8],
                                             const int* __restrict__ dtab,
                                             int dbase, int lane)
{
    #pragma unroll
    for (int r = 0; r < 8; ++r) {
        const int idx = (dbase + r * 64 + lane) * 2;
        const h2 cc = i2h(dtab[idx]);
        const h2 ns = i2h(dtab[idx + 1]);
        a[r] = cc * a[r] + ns * swap_h2(a[r]);
    }
}

// RY on reg qubit QM (packed, real coeffs broadcast into both halves).
template<int QM>
__device__ __forceinline__ void regY_h(h2 (&a)[8], h2 A2, h2 B2, h2 C2, h2 D2)
{
    #pragma unroll
    for (int r = 0; r < 8; ++r) {
        if (!(r & QM)) {
            const int r1 = r | QM;
            const h2 x0 = a[r], x1 = a[r1];
            a[r]  = A2 * x0 + B2 * x1;
            a[r1] = C2 * x0 + D2 * x1;
        }
    }
}

// RY on lane qubit LM: out = c2*self + sp2*partner (one b32 shuffle/amp).
template<int LM>
__device__ __forceinline__ void laneY_h(h2 (&a)[8], int lane, h2 c2, h2 sp2)
{
    #pragma unroll
    for (int r = 0; r < 8; ++r) {
        const h2 p = i2h(shfl_i<LM>(h2i(a[r]), lane));
        a[r] = c2 * a[r] + sp2 * p;
    }
}

// Full RY layer. yt: 9 gates x 3 packed ints {cc},{ss},{nss}.
// sw0/sw1: deferred-CNOT column swaps on q0/q1 (verified R5 mechanism).
__device__ __forceinline__ void apply_Y_h(h2 (&a)[8], int lane,
                                          const int* __restrict__ yt,
                                          bool sw0, bool sw1)
{
    {   const int cc = yt[0], ss = yt[1], ns = yt[2];
        regY_h<1>(a, i2h(sw0 ? ns : cc), i2h(sw0 ? cc : ns),
                     i2h(sw0 ? cc : ss), i2h(sw0 ? ss : cc)); }
    {   const int cc = yt[3], ss = yt[4], ns = yt[5];
        regY_h<2>(a, i2h(sw1 ? ns : cc), i2h(sw1 ? cc : ns),
                     i2h(sw1 ? cc : ss), i2h(sw1 ? ss : cc)); }
    {   regY_h<4>(a, i2h(yt[6]), i2h(yt[8]), i2h(yt[7]), i2h(yt[6])); }
    {   laneY_h<1>(a, lane, i2h(yt[9]),  i2h((lane & 1)        ? yt[10] : yt[11])); }
    {   laneY_h<2>(a, lane, i2h(yt[12]), i2h(((lane >> 1) & 1) ? yt[13] : yt[14])); }
    {   laneY_h<4>(a, lane, i2h(yt[15]), i2h(((lane >> 2) & 1) ? yt[16] : yt[17])); }
    {   laneY_h<8>(a, lane, i2h(yt[18]), i2h(((lane >> 3) & 1) ? yt[19] : yt[20])); }
    {   laneY_h<16>(a, lane, i2h(yt[21]), i2h(((lane >> 4) & 1) ? yt[22] : yt[23])); }
    {   laneY_h<32>(a, lane, i2h(yt[24]), i2h(((lane >> 5) & 1) ? yt[25] : yt[26])); }
}

// ---- Precompute (weights-only).
// ws layout (floats): [0..144) rot fp32; ints at ws+144: ytab 54 ints
// (18 gates x {cc,ss,nss}); ints at ws+208: dtab 3*8*64*2 = 3072 ints.
__global__ void precomp_kernel(const float* __restrict__ w, float* __restrict__ ws)
{
    const int tid = threadIdx.x;
    float* rot = ws;
    int* ytab = (int*)(ws + 144);
    int* dtab = (int*)(ws + 208);
    if (tid < 18) {
        const float phi = w[tid*3 + 0], theta = w[tid*3 + 1], omega = w[tid*3 + 2];
        const float ct = cosf(0.5f * theta), st = sinf(0.5f * theta);
        const float apo = 0.5f * (phi + omega), amo = 0.5f * (phi - omega);
        const float ca = cosf(apo), sa = sinf(apo);
        const float cm = cosf(amo), sm = sinf(amo);
        float* m = rot + tid * 8;
        m[0] =  ca * ct; m[1] = -sa * ct;   // u00
        m[2] = -cm * st; m[3] = -sm * st;   // u01
        m[4] =  cm * st; m[5] = -sm * st;   // u10
        m[6] =  ca * ct; m[7] =  sa * ct;   // u11
        const _Float16 ch = (_Float16)ct, sh = (_Float16)st;
        h2 cc; cc.x = ch;  cc.y = ch;
        h2 ss; ss.x = sh;  ss.y = sh;
        h2 ns; ns.x = -sh; ns.y = -sh;
        ytab[tid*3 + 0] = h2i(cc);
        ytab[tid*3 + 1] = h2i(ss);
        ytab[tid*3 + 2] = h2i(ns);
    }
    if (tid < 192) {
        // ring1 pull-back masks (row-update rule; procedure verified vs ring2)
        const int vmask[9] = {0x1FE,0x003,0x007,0x00F,0x01F,0x03F,0x07F,0x0FF,0x1FF};
        // ring2 pull-back masks (HW-verified R4/R5)
        const int wmask[9] = {0x0AB,0x157,0x005,0x00A,0x015,0x02A,0x055,0x0AA,0x155};
        const int d = tid >> 6, lane = tid & 63;
        for (int r = 0; r < 8; ++r) {
            const int p = (lane << 3) | r;
            float ang = 0.f;
            for (int q = 0; q < 9; ++q) {
                if (d == 0) {            // D_A: conj(Phi_l1) through ring1
                    const float lam = -0.5f * w[(9 + q)*3 + 0];
                    ang += (__popc(p & vmask[q]) & 1) ? -lam : lam;
                } else if (d == 1) {     // D_B: conj(Phi_l0) thru ring2 + Omega_l1
                    const float lam = -0.5f * w[q*3 + 0];
                    ang += (__popc(p & wmask[q]) & 1) ? -lam : lam;
                    const float lm2 = -0.5f * w[(9 + q)*3 + 2];
                    ang += ((p >> q) & 1) ? -lm2 : lm2;
                } else {                 // D_C: conj(Phi_l1) thru ring1 + Omega_l0
                    const float lam = -0.5f * w[(9 + q)*3 + 0];
                    ang += (__popc(p & vmask[q]) & 1) ? -lam : lam;
                    const float lm2 = -0.5f * w[q*3 + 2];
                    ang += ((p >> q) & 1) ? -lm2 : lm2;
                }
            }
            const float c = cosf(ang), s = sinf(ang);
            h2 cc;  cc.x = (_Float16)c;    cc.y = (_Float16)c;
            h2 nsp; nsp.x = (_Float16)(-s); nsp.y = (_Float16)s;  // {-s,+s}
            const int idx = ((d*8 + r)*64 + lane)*2;
            dtab[idx + 0] = h2i(cc);
            dtab[idx + 1] = h2i(nsp);
        }
    }
}

// sign-apply: v * (-1)^par
__device__ __forceinline__ float sgn_apply(float v, int par) {
    return __int_as_float(__float_as_int(v) ^ (par << 31));
}

__global__ __launch_bounds__(PPB * 64, 6) void qconv_kernel(
    const float* __restrict__ x,      // (8, 1, 128, 128)
    const float* __restrict__ ws,     // precomp tables
    float* __restrict__ out)          // (8, 9, 63, 63)
{
    const float* rot  = ws;
    const int* ytab = (const int*)(ws + 144);
    const int* dtab = (const int*)(ws + 208);

    const int lane  = threadIdx.x & 63;
    const int wv    = threadIdx.x >> 6;
    const int patch = blockIdx.x * PPB + wv;
    if (patch >= N_PATCH_TOTAL) return;          // wave-uniform (never taken)

    const int b   = patch / (OUT_HW * OUT_HW);
    const int rem = patch - b * (OUT_HW * OUT_HW);
    const int oy  = rem / OUT_HW;
    const int ox  = rem - oy * OUT_HW;

    const float* xp = x + b * 16384 + (oy * 2) * 128 + (ox * 2);

    // ---- Product state after full RotL0 * RX, in fp32 (verified R5):
    float ar[8], ai[8];
    {
        float Lr = 1.0f, Li = 0.0f;
        #pragma unroll
        for (int q = 3; q < 9; ++q) {
            const float a = xp[(q / 3) * 128 + (q % 3)];
            float s, c;
            __sincosf(0.5f * a, &s, &c);
            const float* R = rot + 8 * q;
            const float alr = c*R[0] + s*R[3], ali = c*R[1] - s*R[2];
            const float ber = c*R[4] + s*R[7], bei = c*R[5] - s*R[6];
            const int bit = (lane >> (q - 3)) & 1;
            const float fr = bit ? ber : alr;
            const float fi = bit ? bei : ali;
            const float nr = Lr*fr - Li*fi;
            const float ni = Lr*fi + Li*fr;
            Lr = nr; Li = ni;
        }
        float alr[3], ali_[3], ber[3], bei[3];
        #pragma unroll
        for (int q = 0; q < 3; ++q) {
            const float a = xp[(q / 3) * 128 + (q % 3)];
            float s, c;
            __sincosf(0.5f * a, &s, &c);
            const float* R = rot + 8 * q;
            alr[q] = c*R[0] + s*R[3]; ali_[q] = c*R[1] - s*R[2];
            ber[q] = c*R[4] + s*R[7]; bei[q] = c*R[5] - s*R[6];
        }
        float c01r[4], c01i[4];
        #pragma unroll
        for (int j = 0; j < 4; ++j) {
            const float f0r = (j & 1) ? ber[0] : alr[0];
            const float f0i = (j & 1) ? bei[0] : ali_[0];
            const float f1r = (j & 2) ? ber[1] : alr[1];
            const float f1i = (j & 2) ? bei[1] : ali_[1];
            c01r[j] = f0r*f1r - f0i*f1i;
            c01i[j] = f0r*f1i + f0i*f1r;
        }
        #pragma unroll
        for (int r = 0; r < 8; ++r) {
            const float f2r = (r & 4) ? ber[2] : alr[2];
            const float f2i = (r & 4) ? bei[2] : ali_[2];
            const float gr = c01r[r & 3]*f2r - c01i[r & 3]*f2i;
            const float gi = c01r[r & 3]*f2i + c01i[r & 3]*f2r;
            ar[r] = gr*Lr - gi*Li;
            ai[r] = gr*Li + gi*Lr;
        }
    }

    // Pack into fp16 complex (v_cvt_pkrtz_f16_f32; bit_cast fixes the
    // __fp16x2 vs _Float16x2 type mismatch that broke R10's compile)
    h2 a[8];
    #pragma unroll
    for (int r = 0; r < 8; ++r) {
        a[r] = __builtin_bit_cast(h2, __builtin_amdgcn_cvt_pkrtz(ar[r], ai[r]));
    }

    const bool b4 = ((lane >> 4) & 1) != 0;   // amp-index bit 7 (qubit 7)
    const bool b5 = ((lane >> 5) & 1) != 0;   // amp-index bit 8 (qubit 8)

    // U = Y1 R1 D_C Y0 R2 D_B Y1 R1 D_A |build>, measured with ring2 masks.
    apply_diag_h(a, dtab, 0 * 512, lane);             // D_A
    ring1_partial_h(a, lane);                         // cnot(8,0) -> Y q0 swap
    apply_Y_h(a, lane, ytab + 27, b5, false);         // Y(l=1)
    apply_diag_h(a, dtab, 1 * 512, lane);             // D_B
    ring2_partial_h(a, lane);                         // (7,0),(8,1) -> Y q0/q1
    apply_Y_h(a, lane, ytab + 0, b4, b5);             // Y(l=0)
    apply_diag_h(a, dtab, 2 * 512, lane);             // D_C
    ring1_partial_h(a, lane);                         // cnot(8,0) -> Y q0 swap
    apply_Y_h(a, lane, ytab + 27, b5, false);         // Y(l=1)
    // final Omega(l=1) dropped; final ring2 absorbed into masks below.

    // ---- Measurement: e_q = sum_p (-1)^{parity(p & w_q)} |amp_p|^2
    float p[8];
    #pragma unroll
    for (int r = 0; r < 8; ++r) {
        const float xr = (float)a[r].x, xi = (float)a[r].y;
        p[r] = xr*xr + xi*xi;
    }

    const float S3 = (p[0]+p[3]+p[4]+p[7]) - (p[1]+p[2]+p[5]+p[6]);
    const float S7 = (p[0]+p[3]+p[5]+p[6]) - (p[1]+p[2]+p[4]+p[7]);
    const float S5 = (p[0]+p[2]+p[5]+p[7]) - (p[1]+p[3]+p[4]+p[6]);
    const float S2 = (p[0]+p[1]+p[4]+p[5]) - (p[2]+p[3]+p[6]+p[7]);

    const int c0 = lane & 1, c1 = (lane >> 1) & 1, c2 = (lane >> 2) & 1;
    const int c3 = (lane >> 3) & 1, c4 = (lane >> 4) & 1, c5 = (lane >> 5) & 1;
    const int p05 = c0 ^ c2, p0A = c1 ^ c3;
    const int p15 = p05 ^ c4, p2A = p0A ^ c5;

    float e[9];
    e[0] = sgn_apply(S3, p15);   // w0 = 0x0AB
    e[1] = sgn_apply(S7, p2A);   // w1 = 0x157
    e[2] = S5;                   // w2 = 0x005
    e[3] = sgn_apply(S2, c0);    // w3 = 0x00A
    e[4] = sgn_apply(S5, c1);    // w4 = 0x015
    e[5] = sgn_apply(S2, p05);   // w5 = 0x02A
    e[6] = sgn_apply(S5, p0A);   // w6 = 0x055
    e[7] = sgn_apply(S2, p15);   // w7 = 0x0AA
    e[8] = sgn_apply(S5, p2A);   // w8 = 0x155

    #pragma unroll
    for (int q = 0; q < 9; ++q) e[q] += shfl_f<1>(e[q], lane);
    #pragma unroll
    for (int q = 0; q < 9; ++q) e[q] += shfl_f<2>(e[q], lane);
    #pragma unroll
    for (int q = 0; q < 9; ++q) e[q] += shfl_f<4>(e[q], lane);
    #pragma unroll
    for (int q = 0; q < 9; ++q) e[q] += shfl_f<8>(e[q], lane);
    #pragma unroll
    for (int q = 0; q < 9; ++q) e[q] += shfl_f<16>(e[q], lane);
    #pragma unroll
    for (int q = 0; q < 9; ++q) e[q] += shfl_f<32>(e[q], lane);

    float v = e[0];
    v = (lane == 1) ? e[1] : v;
    v = (lane == 2) ? e[2] : v;
    v = (lane == 3) ? e[3] : v;
    v = (lane == 4) ? e[4] : v;
    v = (lane == 5) ? e[5] : v;
    v = (lane == 6) ? e[6] : v;
    v = (lane == 7) ? e[7] : v;
    v = (lane == 8) ? e[8] : v;
    if (lane < 9) {
        out[(b * 9 + lane) * (OUT_HW * OUT_HW) + oy * OUT_HW + ox] = v;
    }
}

} // anonymous namespace

extern "C" void kernel_launch(void* const* d_in, const int* in_sizes, int n_in,
                              void* d_out, int out_size, void* d_ws, size_t ws_size,
                              hipStream_t stream)
{
    const float* x = (const float*)d_in[0];   // (8,1,128,128) float32
    const float* w = (const float*)d_in[1];   // (2,9,3) float32
    float* ws = (float*)d_ws;                 // ~3.3k floats scratch
    float* out = (float*)d_out;               // (8,9,63,63) float32

    precomp_kernel<<<1, 256, 0, stream>>>(w, ws);
    qconv_kernel<<<N_PATCH_TOTAL / PPB, PPB * 64, 0, stream>>>(x, ws, out);
}